// Round 1
// baseline (953.942 us; speedup 1.0000x reference)
//
#include <hip/hip_runtime.h>
#include <math.h>

#define N_NODES 50000
#define N_EDGES 800000
#define HC 64
#define HID 16
#define EDIM 16
#define NGRAPH 2000
#define BN_EPS 1e-5f
#define QKVS_NODES 32

// ---------- CSR build ----------
__global__ void count_deg(const int* __restrict__ ei, int* __restrict__ deg) {
    int e = blockIdx.x * blockDim.x + threadIdx.x;
    if (e < N_EDGES) atomicAdd(&deg[ei[N_EDGES + e]], 1);
}

__global__ __launch_bounds__(1024) void scan_deg(const int* __restrict__ deg,
                                                 int* __restrict__ row_ptr,
                                                 int* __restrict__ next_ptr) {
    __shared__ int s[1024];
    int tid = threadIdx.x;
    int off = 0;
    for (int base = 0; base < N_NODES; base += 1024) {
        int i = base + tid;
        int v = (i < N_NODES) ? deg[i] : 0;
        s[tid] = v;
        __syncthreads();
        for (int d = 1; d < 1024; d <<= 1) {
            int t = (tid >= d) ? s[tid - d] : 0;
            __syncthreads();
            s[tid] += t;
            __syncthreads();
        }
        int incl = s[tid];
        int total = s[1023];
        if (i < N_NODES) { row_ptr[i] = off + incl - v; next_ptr[i] = off + incl - v; }
        off += total;
        __syncthreads();
    }
    if (tid == 0) row_ptr[N_NODES] = off;
}

__global__ void scatter_edges(const int* __restrict__ ei, int* __restrict__ next_ptr,
                              int* __restrict__ src_s, int* __restrict__ eid_s) {
    int e = blockIdx.x * blockDim.x + threadIdx.x;
    if (e < N_EDGES) {
        int d = ei[N_EDGES + e];
        int p = atomicAdd(&next_ptr[d], 1);
        src_s[p] = ei[e];
        eid_s[p] = e;
    }
}

// ---------- fused Q/K/V/Skip GEMM: out[sel] = x @ W[sel] + b[sel] ----------
__global__ __launch_bounds__(256) void qkvs_kernel(
    const float* __restrict__ x,
    const float* __restrict__ Wq, const float* __restrict__ bq,
    const float* __restrict__ Wk, const float* __restrict__ bk,
    const float* __restrict__ Wv, const float* __restrict__ bv,
    const float* __restrict__ Ws, const float* __restrict__ bs,
    float* __restrict__ Qo, float* __restrict__ Ko,
    float* __restrict__ Vo, float* __restrict__ So) {
    __shared__ float xs[QKVS_NODES][HC];
    int tid = threadIdx.x;
    int n0 = blockIdx.x * QKVS_NODES;
    // stage 32 x-rows (coalesced float4)
    for (int c = tid; c < QKVS_NODES * HC / 4; c += 256) {
        int row = c >> 4, col4 = c & 15;
        int n = n0 + row;
        float4 v = (n < N_NODES) ? ((const float4*)(x + (size_t)n * HC))[col4]
                                 : make_float4(0.f, 0.f, 0.f, 0.f);
        ((float4*)&xs[row][0])[col4] = v;
    }
    __syncthreads();
    int sel = tid >> 6;   // which of Q/K/V/S this wave computes
    int j   = tid & 63;   // output column
    const float* W = (sel == 0) ? Wq : (sel == 1) ? Wk : (sel == 2) ? Wv : Ws;
    const float* B = (sel == 0) ? bq : (sel == 1) ? bk : (sel == 2) ? bv : bs;
    float* Out     = (sel == 0) ? Qo : (sel == 1) ? Ko : (sel == 2) ? Vo : So;
    float bias = B[j];
    float acc[QKVS_NODES];
#pragma unroll
    for (int n = 0; n < QKVS_NODES; n++) acc[n] = bias;
    for (int i4 = 0; i4 < HC / 4; i4++) {
        float w0 = W[(i4 * 4 + 0) * HC + j];
        float w1 = W[(i4 * 4 + 1) * HC + j];
        float w2 = W[(i4 * 4 + 2) * HC + j];
        float w3 = W[(i4 * 4 + 3) * HC + j];
#pragma unroll
        for (int n = 0; n < QKVS_NODES; n++) {
            float4 xv = ((const float4*)&xs[n][0])[i4];  // LDS broadcast
            acc[n] = fmaf(xv.x, w0, acc[n]);
            acc[n] = fmaf(xv.y, w1, acc[n]);
            acc[n] = fmaf(xv.z, w2, acc[n]);
            acc[n] = fmaf(xv.w, w3, acc[n]);
        }
    }
#pragma unroll
    for (int n = 0; n < QKVS_NODES; n++) {
        int node = n0 + n;
        if (node < N_NODES) Out[(size_t)node * HC + j] = acc[n];
    }
}

// ---------- attention + skip + BN + ReLU: one wave per node ----------
__global__ __launch_bounds__(256) void attn_kernel(
    const float* __restrict__ Qf, const float* __restrict__ Kf,
    const float* __restrict__ Vf, const float* __restrict__ Sf,
    const int* __restrict__ row_ptr, const int* __restrict__ src_s,
    const int* __restrict__ eid_s, const float* __restrict__ edge_attr,
    const float* __restrict__ We,
    const float* __restrict__ bng, const float* __restrict__ bnb,
    const float* __restrict__ bnm, const float* __restrict__ bnv,
    float* __restrict__ x_out) {
    __shared__ float we_s[EDIM * HC];  // 4 KB
    int tid = threadIdx.x;
    for (int c = tid; c < EDIM * HC / 4; c += 256)
        ((float4*)we_s)[c] = ((const float4*)We)[c];
    __syncthreads();

    int node = blockIdx.x * 4 + (tid >> 6);
    if (node >= N_NODES) return;
    int lane = tid & 63;
    int quarter = lane >> 4;   // which edge of each group of 4
    int pos = lane & 15;       // float4 slice of the 64-dim row; head = pos>>2
    int rbeg = row_ptr[node], rend = row_ptr[node + 1];

    float4 q4 = ((const float4*)(Qf + (size_t)node * HC))[pos];
    float m = -1e30f, den = 0.f;
    float4 acc = make_float4(0.f, 0.f, 0.f, 0.f);

    for (int j = rbeg + quarter; j < rend; j += 4) {
        int s = src_s[j];
        int e = eid_s[j];
        float4 k4 = ((const float4*)(Kf + (size_t)s * HC))[pos];
        float4 v4 = ((const float4*)(Vf + (size_t)s * HC))[pos];
        const float4* ea = (const float4*)(edge_attr + (size_t)e * EDIM);
        float4 ea0 = ea[0], ea1 = ea[1], ea2 = ea[2], ea3 = ea[3];
        float eav[16] = {ea0.x, ea0.y, ea0.z, ea0.w, ea1.x, ea1.y, ea1.z, ea1.w,
                         ea2.x, ea2.y, ea2.z, ea2.w, ea3.x, ea3.y, ea3.z, ea3.w};
        float4 e4 = make_float4(0.f, 0.f, 0.f, 0.f);
#pragma unroll
        for (int t = 0; t < EDIM; t++) {
            float4 w4 = *((const float4*)(we_s + t * HC + pos * 4));
            e4.x = fmaf(eav[t], w4.x, e4.x);
            e4.y = fmaf(eav[t], w4.y, e4.y);
            e4.z = fmaf(eav[t], w4.z, e4.z);
            e4.w = fmaf(eav[t], w4.w, e4.w);
        }
        float4 kk = make_float4(k4.x + e4.x, k4.y + e4.y, k4.z + e4.z, k4.w + e4.w);
        float dot = q4.x * kk.x + q4.y * kk.y + q4.z * kk.z + q4.w * kk.w;
        dot += __shfl_xor(dot, 1);
        dot += __shfl_xor(dot, 2);          // 4 lanes of a head now hold the head dot
        float logit = dot * 0.25f;          // / sqrt(HID=16)
        float mn = fmaxf(m, logit);
        float corr = __expf(m - mn);
        float p = __expf(logit - mn);
        den = den * corr + p;
        acc.x = acc.x * corr + p * (v4.x + e4.x);
        acc.y = acc.y * corr + p * (v4.y + e4.y);
        acc.z = acc.z * corr + p * (v4.z + e4.z);
        acc.w = acc.w * corr + p * (v4.w + e4.w);
        m = mn;
    }
    // merge the 4 quarter-wave softmax states (lanes pos, pos+16, pos+32, pos+48)
#pragma unroll
    for (int off = 16; off <= 32; off <<= 1) {
        float m2 = __shfl_xor(m, off);
        float d2 = __shfl_xor(den, off);
        float ax = __shfl_xor(acc.x, off);
        float ay = __shfl_xor(acc.y, off);
        float az = __shfl_xor(acc.z, off);
        float aw = __shfl_xor(acc.w, off);
        float mn = fmaxf(m, m2);
        float c1 = __expf(m - mn), c2 = __expf(m2 - mn);
        den = den * c1 + d2 * c2;
        acc.x = acc.x * c1 + ax * c2;
        acc.y = acc.y * c1 + ay * c2;
        acc.z = acc.z * c1 + az * c2;
        acc.w = acc.w * c1 + aw * c2;
        m = mn;
    }
    float inv = (rend > rbeg) ? 1.f / den : 0.f;
    float4 sk = ((const float4*)(Sf + (size_t)node * HC))[pos];
    float4 o = make_float4(acc.x * inv + sk.x, acc.y * inv + sk.y,
                           acc.z * inv + sk.z, acc.w * inv + sk.w);
    // BN (eval) + ReLU
    float4 g4 = ((const float4*)bng)[pos];
    float4 b4 = ((const float4*)bnb)[pos];
    float4 m4 = ((const float4*)bnm)[pos];
    float4 vv4 = ((const float4*)bnv)[pos];
    o.x = fmaxf((o.x - m4.x) * rsqrtf(vv4.x + BN_EPS) * g4.x + b4.x, 0.f);
    o.y = fmaxf((o.y - m4.y) * rsqrtf(vv4.y + BN_EPS) * g4.y + b4.y, 0.f);
    o.z = fmaxf((o.z - m4.z) * rsqrtf(vv4.z + BN_EPS) * g4.z + b4.z, 0.f);
    o.w = fmaxf((o.w - m4.w) * rsqrtf(vv4.w + BN_EPS) * g4.w + b4.w, 0.f);
    if (quarter == 0) ((float4*)(x_out + (size_t)node * HC))[pos] = o;
}

// ---------- mean-pool ----------
__global__ void pool_kernel(const float* __restrict__ x, const int* __restrict__ batch,
                            float* __restrict__ pooled, int* __restrict__ cnt) {
    int t = blockIdx.x * blockDim.x + threadIdx.x;
    int node = t >> 4, p = t & 15;
    if (node >= N_NODES) return;
    int g = batch[node];
    float4 v = ((const float4*)(x + (size_t)node * HC))[p];
    float* pb = pooled + (size_t)g * HC + p * 4;
    atomicAdd(pb + 0, v.x);
    atomicAdd(pb + 1, v.y);
    atomicAdd(pb + 2, v.z);
    atomicAdd(pb + 3, v.w);
    if (p == 0) atomicAdd(&cnt[g], 1);
}

// ---------- MLP head ----------
__global__ void head_kernel(const float* __restrict__ pooled, const int* __restrict__ cnt,
                            const float* __restrict__ fc1_w, const float* __restrict__ fc1_b,
                            const float* __restrict__ fc2_w, const float* __restrict__ fc2_b,
                            float* __restrict__ out) {
    int g = blockIdx.x * blockDim.x + threadIdx.x;
    if (g >= NGRAPH) return;
    float inv = 1.f / fmaxf((float)cnt[g], 1.f);
    float p[HC];
#pragma unroll
    for (int i = 0; i < HC; i++) p[i] = pooled[(size_t)g * HC + i] * inv;
    float o = fc2_b[0];
#pragma unroll
    for (int j = 0; j < HID; j++) {
        float a = fc1_b[j];
#pragma unroll
        for (int i = 0; i < HC; i++) a = fmaf(p[i], fc1_w[i * HID + j], a);
        o = fmaf(fmaxf(a, 0.f), fc2_w[j], o);
    }
    out[g] = o;
}

extern "C" void kernel_launch(void* const* d_in, const int* in_sizes, int n_in,
                              void* d_out, int out_size, void* d_ws, size_t ws_size,
                              hipStream_t stream) {
    const float* x         = (const float*)d_in[0];
    const int*   ei        = (const int*)d_in[1];
    const float* edge_attr = (const float*)d_in[2];
    const int*   batch     = (const int*)d_in[3];
    const float* Wq = (const float*)d_in[4];  const float* bq = (const float*)d_in[5];
    const float* Wk = (const float*)d_in[6];  const float* bk = (const float*)d_in[7];
    const float* Wv = (const float*)d_in[8];  const float* bv = (const float*)d_in[9];
    const float* We = (const float*)d_in[10];
    const float* Ws = (const float*)d_in[11]; const float* bs = (const float*)d_in[12];
    const float* bng = (const float*)d_in[13]; const float* bnb = (const float*)d_in[14];
    const float* bnm = (const float*)d_in[15]; const float* bnv = (const float*)d_in[16];
    const float* fc1_w = (const float*)d_in[17]; const float* fc1_b = (const float*)d_in[18];
    const float* fc2_w = (const float*)d_in[19]; const float* fc2_b = (const float*)d_in[20];
    float* out = (float*)d_out;

    char* wp = (char*)d_ws;
    auto alloc = [&](size_t b) { void* p = (void*)wp; wp += (b + 255) & ~(size_t)255; return p; };
    float* xA      = (float*)alloc((size_t)N_NODES * HC * 4);
    float* xB      = (float*)alloc((size_t)N_NODES * HC * 4);
    float* Qb      = (float*)alloc((size_t)N_NODES * HC * 4);
    float* Kb      = (float*)alloc((size_t)N_NODES * HC * 4);
    float* Vb      = (float*)alloc((size_t)N_NODES * HC * 4);
    float* Sb      = (float*)alloc((size_t)N_NODES * HC * 4);
    int*   deg     = (int*)alloc((size_t)N_NODES * 4);
    int*   row_ptr = (int*)alloc((size_t)(N_NODES + 1) * 4);
    int*   nxt     = (int*)alloc((size_t)N_NODES * 4);
    int*   src_s   = (int*)alloc((size_t)N_EDGES * 4);
    int*   eid_s   = (int*)alloc((size_t)N_EDGES * 4);
    float* pooled  = (float*)alloc((size_t)NGRAPH * HC * 4);
    int*   cnt     = (int*)alloc((size_t)NGRAPH * 4);

    hipMemsetAsync(deg, 0, (size_t)N_NODES * 4, stream);
    hipMemsetAsync(pooled, 0, (size_t)NGRAPH * HC * 4, stream);
    hipMemsetAsync(cnt, 0, (size_t)NGRAPH * 4, stream);

    count_deg<<<(N_EDGES + 255) / 256, 256, 0, stream>>>(ei, deg);
    scan_deg<<<1, 1024, 0, stream>>>(deg, row_ptr, nxt);
    scatter_edges<<<(N_EDGES + 255) / 256, 256, 0, stream>>>(ei, nxt, src_s, eid_s);

    const float* xin = x;
    float* bufs[2] = {xA, xB};
    for (int l = 0; l < 3; l++) {
        float* xout = bufs[l & 1];
        qkvs_kernel<<<(N_NODES + QKVS_NODES - 1) / QKVS_NODES, 256, 0, stream>>>(
            xin, Wq + l * HC * HC, bq + l * HC, Wk + l * HC * HC, bk + l * HC,
            Wv + l * HC * HC, bv + l * HC, Ws + l * HC * HC, bs + l * HC,
            Qb, Kb, Vb, Sb);
        attn_kernel<<<(N_NODES + 3) / 4, 256, 0, stream>>>(
            Qb, Kb, Vb, Sb, row_ptr, src_s, eid_s, edge_attr, We + l * EDIM * HC,
            bng + l * HC, bnb + l * HC, bnm + l * HC, bnv + l * HC, xout);
        xin = xout;
    }
    pool_kernel<<<(N_NODES * 16 + 255) / 256, 256, 0, stream>>>(xin, batch, pooled, cnt);
    head_kernel<<<(NGRAPH + 255) / 256, 256, 0, stream>>>(pooled, cnt, fc1_w, fc1_b,
                                                          fc2_w, fc2_b, out);
}

// Round 2
// 881.529 us; speedup vs baseline: 1.0821x; 1.0821x over previous
//
#include <hip/hip_runtime.h>
#include <math.h>

#define N_NODES 50000
#define N_EDGES 800000
#define HC 64
#define HID 16
#define EDIM 16
#define NGRAPH 2000
#define BN_EPS 1e-5f
#define QKVS_NODES 32
#define SCAN_NBLK ((N_NODES + 255) / 256)   // 196

// ---------- CSR build ----------
__global__ void count_deg(const int* __restrict__ ei, int* __restrict__ deg) {
    int e = blockIdx.x * blockDim.x + threadIdx.x;
    if (e < N_EDGES) atomicAdd(&deg[ei[N_EDGES + e]], 1);
}

__global__ __launch_bounds__(256) void scan1(const int* __restrict__ deg, int* __restrict__ bsum) {
    __shared__ int s[256];
    int tid = threadIdx.x;
    int i = blockIdx.x * 256 + tid;
    s[tid] = (i < N_NODES) ? deg[i] : 0;
    __syncthreads();
    for (int d = 128; d > 0; d >>= 1) {
        if (tid < d) s[tid] += s[tid + d];
        __syncthreads();
    }
    if (tid == 0) bsum[blockIdx.x] = s[0];
}

__global__ __launch_bounds__(256) void scan2(const int* __restrict__ bsum, int* __restrict__ boff) {
    __shared__ int s[256];
    int tid = threadIdx.x;
    int v = (tid < SCAN_NBLK) ? bsum[tid] : 0;
    s[tid] = v;
    __syncthreads();
    for (int d = 1; d < 256; d <<= 1) {
        int t = (tid >= d) ? s[tid - d] : 0;
        __syncthreads();
        s[tid] += t;
        __syncthreads();
    }
    boff[tid] = s[tid] - v;  // exclusive
}

__global__ __launch_bounds__(256) void scan3(const int* __restrict__ deg, const int* __restrict__ boff,
                                             int* __restrict__ row_ptr, int* __restrict__ nxt) {
    __shared__ int s[256];
    int tid = threadIdx.x;
    int i = blockIdx.x * 256 + tid;
    int v = (i < N_NODES) ? deg[i] : 0;
    s[tid] = v;
    __syncthreads();
    for (int d = 1; d < 256; d <<= 1) {
        int t = (tid >= d) ? s[tid - d] : 0;
        __syncthreads();
        s[tid] += t;
        __syncthreads();
    }
    int excl = s[tid] - v + boff[blockIdx.x];
    if (i < N_NODES) { row_ptr[i] = excl; nxt[i] = excl; }
    if (i == 0) row_ptr[N_NODES] = N_EDGES;
}

__global__ void scatter_edges(const int* __restrict__ ei, int* __restrict__ next_ptr,
                              int* __restrict__ src_s, int* __restrict__ eid_s) {
    int e = blockIdx.x * blockDim.x + threadIdx.x;
    if (e < N_EDGES) {
        int d = ei[N_EDGES + e];
        int p = atomicAdd(&next_ptr[d], 1);
        src_s[p] = ei[e];
        eid_s[p] = e;
    }
}

// permute edge_attr into CSR edge order (coalesced writes, random row reads once)
__global__ void permute_ea(const int* __restrict__ eid_s, const float* __restrict__ edge_attr,
                           float* __restrict__ ea_s) {
    int t = blockIdx.x * blockDim.x + threadIdx.x;
    if (t >= N_EDGES * 4) return;
    int p = t >> 2, c = t & 3;
    int e = eid_s[p];
    ((float4*)ea_s)[p * 4 + c] = ((const float4*)edge_attr)[e * 4 + c];
}

// ---------- fused Q/K/V/Skip GEMM ----------
// K,V interleave into KV[node][128]; x-row loads are wave-uniform -> scalar loads
__global__ __launch_bounds__(256) void qkvs_kernel(
    const float* __restrict__ x,
    const float* __restrict__ Wq, const float* __restrict__ bq,
    const float* __restrict__ Wk, const float* __restrict__ bk,
    const float* __restrict__ Wv, const float* __restrict__ bv,
    const float* __restrict__ Ws, const float* __restrict__ bs,
    float* __restrict__ Qo, float* __restrict__ KVo, float* __restrict__ So) {
    int tid = threadIdx.x;
    int n0 = blockIdx.x * QKVS_NODES;
    int sel = tid >> 6;
    int j = tid & 63;
    const float* W; const float* B; float* Out; int stride; int off;
    if (sel == 0)      { W = Wq; B = bq; Out = Qo;  stride = HC;     off = 0;  }
    else if (sel == 1) { W = Wk; B = bk; Out = KVo; stride = 2 * HC; off = 0;  }
    else if (sel == 2) { W = Wv; B = bv; Out = KVo; stride = 2 * HC; off = HC; }
    else               { W = Ws; B = bs; Out = So;  stride = HC;     off = 0;  }
    float bias = B[j];
    float acc[QKVS_NODES];
#pragma unroll
    for (int n = 0; n < QKVS_NODES; n++) acc[n] = bias;

    if (n0 + QKVS_NODES <= N_NODES) {
        for (int i4 = 0; i4 < HC / 4; i4++) {
            float w0 = W[(i4 * 4 + 0) * HC + j];
            float w1 = W[(i4 * 4 + 1) * HC + j];
            float w2 = W[(i4 * 4 + 2) * HC + j];
            float w3 = W[(i4 * 4 + 3) * HC + j];
#pragma unroll
            for (int n = 0; n < QKVS_NODES; n++) {
                float4 xv = *(const float4*)(x + (size_t)(n0 + n) * HC + i4 * 4);  // uniform -> s_load
                acc[n] = fmaf(xv.x, w0, acc[n]);
                acc[n] = fmaf(xv.y, w1, acc[n]);
                acc[n] = fmaf(xv.z, w2, acc[n]);
                acc[n] = fmaf(xv.w, w3, acc[n]);
            }
        }
#pragma unroll
        for (int n = 0; n < QKVS_NODES; n++)
            Out[(size_t)(n0 + n) * stride + off + j] = acc[n];
    } else {
        for (int i4 = 0; i4 < HC / 4; i4++) {
            float w0 = W[(i4 * 4 + 0) * HC + j];
            float w1 = W[(i4 * 4 + 1) * HC + j];
            float w2 = W[(i4 * 4 + 2) * HC + j];
            float w3 = W[(i4 * 4 + 3) * HC + j];
#pragma unroll
            for (int n = 0; n < QKVS_NODES; n++) {
                if (n0 + n < N_NODES) {
                    float4 xv = *(const float4*)(x + (size_t)(n0 + n) * HC + i4 * 4);
                    acc[n] = fmaf(xv.x, w0, acc[n]);
                    acc[n] = fmaf(xv.y, w1, acc[n]);
                    acc[n] = fmaf(xv.z, w2, acc[n]);
                    acc[n] = fmaf(xv.w, w3, acc[n]);
                }
            }
        }
#pragma unroll
        for (int n = 0; n < QKVS_NODES; n++)
            if (n0 + n < N_NODES) Out[(size_t)(n0 + n) * stride + off + j] = acc[n];
    }
}

// ---------- attention + skip + BN + ReLU: one wave per node ----------
__global__ __launch_bounds__(256) void attn_kernel(
    const float* __restrict__ Qf, const float* __restrict__ KV,
    const float* __restrict__ Sf,
    const int* __restrict__ row_ptr, const int* __restrict__ src_s,
    const float* __restrict__ ea_s, const float* __restrict__ We,
    const float* __restrict__ bng, const float* __restrict__ bnb,
    const float* __restrict__ bnm, const float* __restrict__ bnv,
    float* __restrict__ x_out) {
    __shared__ float we_s[EDIM * HC];  // 4 KB
    int tid = threadIdx.x;
    for (int c = tid; c < EDIM * HC / 4; c += 256)
        ((float4*)we_s)[c] = ((const float4*)We)[c];
    __syncthreads();

    int node = blockIdx.x * 4 + (tid >> 6);   // 50000/4 = 12500 blocks exactly
    int lane = tid & 63;
    int quarter = lane >> 4;
    int pos = lane & 15;
    int rbeg = row_ptr[node], rend = row_ptr[node + 1];

    float4 q4 = ((const float4*)(Qf + (size_t)node * HC))[pos];
    float m = -1e30f, den = 0.f;
    float4 acc = make_float4(0.f, 0.f, 0.f, 0.f);

    auto proc = [&](float4 k4, float4 v4, float4 ea0, float4 ea1, float4 ea2, float4 ea3) {
        float eav[16] = {ea0.x, ea0.y, ea0.z, ea0.w, ea1.x, ea1.y, ea1.z, ea1.w,
                         ea2.x, ea2.y, ea2.z, ea2.w, ea3.x, ea3.y, ea3.z, ea3.w};
        float4 e4 = make_float4(0.f, 0.f, 0.f, 0.f);
#pragma unroll
        for (int t = 0; t < EDIM; t++) {
            float4 w4 = *((const float4*)(we_s + t * HC + pos * 4));
            e4.x = fmaf(eav[t], w4.x, e4.x);
            e4.y = fmaf(eav[t], w4.y, e4.y);
            e4.z = fmaf(eav[t], w4.z, e4.z);
            e4.w = fmaf(eav[t], w4.w, e4.w);
        }
        float dot = q4.x * (k4.x + e4.x) + q4.y * (k4.y + e4.y)
                  + q4.z * (k4.z + e4.z) + q4.w * (k4.w + e4.w);
        dot += __shfl_xor(dot, 1);
        dot += __shfl_xor(dot, 2);
        float logit = dot * 0.25f;
        float mn = fmaxf(m, logit);
        float corr = __expf(m - mn);
        float p = __expf(logit - mn);
        den = den * corr + p;
        acc.x = acc.x * corr + p * (v4.x + e4.x);
        acc.y = acc.y * corr + p * (v4.y + e4.y);
        acc.z = acc.z * corr + p * (v4.z + e4.z);
        acc.w = acc.w * corr + p * (v4.w + e4.w);
        m = mn;
    };

    int j = rbeg + quarter;
    for (; j + 4 < rend; j += 8) {
        int s0 = src_s[j];
        int s1 = src_s[j + 4];
        const float4* kv0 = (const float4*)(KV + (size_t)s0 * 2 * HC);
        const float4* kv1 = (const float4*)(KV + (size_t)s1 * 2 * HC);
        float4 k0 = kv0[pos], v0 = kv0[16 + pos];
        float4 k1 = kv1[pos], v1 = kv1[16 + pos];
        const float4* ep0 = (const float4*)(ea_s + (size_t)j * EDIM);
        const float4* ep1 = (const float4*)(ea_s + (size_t)(j + 4) * EDIM);
        float4 a00 = ep0[0], a01 = ep0[1], a02 = ep0[2], a03 = ep0[3];
        float4 a10 = ep1[0], a11 = ep1[1], a12 = ep1[2], a13 = ep1[3];
        proc(k0, v0, a00, a01, a02, a03);
        proc(k1, v1, a10, a11, a12, a13);
    }
    if (j < rend) {
        int s0 = src_s[j];
        const float4* kv0 = (const float4*)(KV + (size_t)s0 * 2 * HC);
        float4 k0 = kv0[pos], v0 = kv0[16 + pos];
        const float4* ep0 = (const float4*)(ea_s + (size_t)j * EDIM);
        proc(k0, v0, ep0[0], ep0[1], ep0[2], ep0[3]);
    }

    // merge the 4 quarter-wave softmax states
#pragma unroll
    for (int off = 16; off <= 32; off <<= 1) {
        float m2 = __shfl_xor(m, off);
        float d2 = __shfl_xor(den, off);
        float ax = __shfl_xor(acc.x, off);
        float ay = __shfl_xor(acc.y, off);
        float az = __shfl_xor(acc.z, off);
        float aw = __shfl_xor(acc.w, off);
        float mn = fmaxf(m, m2);
        float c1 = __expf(m - mn), c2 = __expf(m2 - mn);
        den = den * c1 + d2 * c2;
        acc.x = acc.x * c1 + ax * c2;
        acc.y = acc.y * c1 + ay * c2;
        acc.z = acc.z * c1 + az * c2;
        acc.w = acc.w * c1 + aw * c2;
        m = mn;
    }
    float inv = (rend > rbeg) ? 1.f / den : 0.f;
    float4 sk = ((const float4*)(Sf + (size_t)node * HC))[pos];
    float4 o = make_float4(acc.x * inv + sk.x, acc.y * inv + sk.y,
                           acc.z * inv + sk.z, acc.w * inv + sk.w);
    float4 g4 = ((const float4*)bng)[pos];
    float4 b4 = ((const float4*)bnb)[pos];
    float4 m4 = ((const float4*)bnm)[pos];
    float4 vv4 = ((const float4*)bnv)[pos];
    o.x = fmaxf((o.x - m4.x) * rsqrtf(vv4.x + BN_EPS) * g4.x + b4.x, 0.f);
    o.y = fmaxf((o.y - m4.y) * rsqrtf(vv4.y + BN_EPS) * g4.y + b4.y, 0.f);
    o.z = fmaxf((o.z - m4.z) * rsqrtf(vv4.z + BN_EPS) * g4.z + b4.z, 0.f);
    o.w = fmaxf((o.w - m4.w) * rsqrtf(vv4.w + BN_EPS) * g4.w + b4.w, 0.f);
    if (quarter == 0) ((float4*)(x_out + (size_t)node * HC))[pos] = o;
}

// ---------- graph bounds via binary search (batch is sorted) ----------
__global__ void graph_bounds(const int* __restrict__ batch, int* __restrict__ gstart) {
    int g = blockIdx.x * blockDim.x + threadIdx.x;
    if (g > NGRAPH) return;
    int lo = 0, hi = N_NODES;
    while (lo < hi) {
        int mid = (lo + hi) >> 1;
        if (batch[mid] < g) lo = mid + 1; else hi = mid;
    }
    gstart[g] = lo;
}

// ---------- fused mean-pool + MLP head: one wave per graph ----------
__global__ __launch_bounds__(256) void pool_head(
    const float* __restrict__ x, const int* __restrict__ gstart,
    const float* __restrict__ fc1_w, const float* __restrict__ fc1_b,
    const float* __restrict__ fc2_w, const float* __restrict__ fc2_b,
    float* __restrict__ out) {
    __shared__ float ps[4][HC];
    int q = threadIdx.x >> 6;
    int lane = threadIdx.x & 63;
    int g = blockIdx.x * 4 + q;           // 500 blocks * 4 = 2000 exactly
    int beg = gstart[g], end = gstart[g + 1];
    float s = 0.f;
    for (int i = beg; i < end; i++) s += x[(size_t)i * HC + lane];  // coalesced
    float inv = (end > beg) ? 1.f / (float)(end - beg) : 1.f;
    ps[q][lane] = s * inv;
    __syncthreads();
    float o = 0.f;
    if (lane < HID) {
        float a = fc1_b[lane];
#pragma unroll
        for (int i = 0; i < HC; i++) a = fmaf(ps[q][i], fc1_w[i * HID + lane], a);
        o = fmaxf(a, 0.f) * fc2_w[lane];
    }
    o += __shfl_xor(o, 1);
    o += __shfl_xor(o, 2);
    o += __shfl_xor(o, 4);
    o += __shfl_xor(o, 8);
    if (lane == 0) out[g] = o + fc2_b[0];
}

extern "C" void kernel_launch(void* const* d_in, const int* in_sizes, int n_in,
                              void* d_out, int out_size, void* d_ws, size_t ws_size,
                              hipStream_t stream) {
    const float* x         = (const float*)d_in[0];
    const int*   ei        = (const int*)d_in[1];
    const float* edge_attr = (const float*)d_in[2];
    const int*   batch     = (const int*)d_in[3];
    const float* Wq = (const float*)d_in[4];  const float* bq = (const float*)d_in[5];
    const float* Wk = (const float*)d_in[6];  const float* bk = (const float*)d_in[7];
    const float* Wv = (const float*)d_in[8];  const float* bv = (const float*)d_in[9];
    const float* We = (const float*)d_in[10];
    const float* Ws = (const float*)d_in[11]; const float* bs = (const float*)d_in[12];
    const float* bng = (const float*)d_in[13]; const float* bnb = (const float*)d_in[14];
    const float* bnm = (const float*)d_in[15]; const float* bnv = (const float*)d_in[16];
    const float* fc1_w = (const float*)d_in[17]; const float* fc1_b = (const float*)d_in[18];
    const float* fc2_w = (const float*)d_in[19]; const float* fc2_b = (const float*)d_in[20];
    float* out = (float*)d_out;

    char* wp = (char*)d_ws;
    auto alloc = [&](size_t b) { void* p = (void*)wp; wp += (b + 255) & ~(size_t)255; return p; };
    float* xA      = (float*)alloc((size_t)N_NODES * HC * 4);
    float* xB      = (float*)alloc((size_t)N_NODES * HC * 4);
    float* Qb      = (float*)alloc((size_t)N_NODES * HC * 4);
    float* Sb      = (float*)alloc((size_t)N_NODES * HC * 4);
    float* KV      = (float*)alloc((size_t)N_NODES * 2 * HC * 4);
    int*   deg     = (int*)alloc((size_t)N_NODES * 4);
    int*   row_ptr = (int*)alloc((size_t)(N_NODES + 1) * 4);
    int*   nxt     = (int*)alloc((size_t)N_NODES * 4);
    int*   bsum    = (int*)alloc((size_t)256 * 4);
    int*   boff    = (int*)alloc((size_t)256 * 4);
    int*   src_s   = (int*)alloc((size_t)N_EDGES * 4);
    int*   eid_s   = (int*)alloc((size_t)N_EDGES * 4);
    float* ea_s    = (float*)alloc((size_t)N_EDGES * EDIM * 4);
    int*   gstart  = (int*)alloc((size_t)(NGRAPH + 1) * 4);

    hipMemsetAsync(deg, 0, (size_t)N_NODES * 4, stream);

    count_deg<<<(N_EDGES + 255) / 256, 256, 0, stream>>>(ei, deg);
    scan1<<<SCAN_NBLK, 256, 0, stream>>>(deg, bsum);
    scan2<<<1, 256, 0, stream>>>(bsum, boff);
    scan3<<<SCAN_NBLK, 256, 0, stream>>>(deg, boff, row_ptr, nxt);
    scatter_edges<<<(N_EDGES + 255) / 256, 256, 0, stream>>>(ei, nxt, src_s, eid_s);
    permute_ea<<<(N_EDGES * 4 + 255) / 256, 256, 0, stream>>>(eid_s, edge_attr, ea_s);
    graph_bounds<<<(NGRAPH + 1 + 255) / 256, 256, 0, stream>>>(batch, gstart);

    const float* xin = x;
    float* bufs[2] = {xA, xB};
    for (int l = 0; l < 3; l++) {
        float* xout = bufs[l & 1];
        qkvs_kernel<<<(N_NODES + QKVS_NODES - 1) / QKVS_NODES, 256, 0, stream>>>(
            xin, Wq + l * HC * HC, bq + l * HC, Wk + l * HC * HC, bk + l * HC,
            Wv + l * HC * HC, bv + l * HC, Ws + l * HC * HC, bs + l * HC,
            Qb, KV, Sb);
        attn_kernel<<<N_NODES / 4, 256, 0, stream>>>(
            Qb, KV, Sb, row_ptr, src_s, ea_s, We + l * EDIM * HC,
            bng + l * HC, bnb + l * HC, bnm + l * HC, bnv + l * HC, xout);
        xin = xout;
    }
    pool_head<<<NGRAPH / 4, 256, 0, stream>>>(xin, gstart, fc1_w, fc1_b, fc2_w, fc2_b, out);
}

// Round 3
// 833.330 us; speedup vs baseline: 1.1447x; 1.0578x over previous
//
#include <hip/hip_runtime.h>
#include <math.h>

#define N_NODES 50000
#define N_EDGES 800000
#define HC 64
#define HID 16
#define EDIM 16
#define NGRAPH 2000
#define BN_EPS 1e-5f
#define QKVS_NODES 32
#define SCAN_NBLK ((N_NODES + 255) / 256)   // 196

// ---------- CSR build ----------
__global__ void count_deg(const int* __restrict__ ei, int* __restrict__ deg) {
    int e = blockIdx.x * blockDim.x + threadIdx.x;
    if (e < N_EDGES) atomicAdd(&deg[ei[N_EDGES + e]], 1);
}

__global__ __launch_bounds__(256) void scan1(const int* __restrict__ deg, int* __restrict__ bsum) {
    __shared__ int s[256];
    int tid = threadIdx.x;
    int i = blockIdx.x * 256 + tid;
    s[tid] = (i < N_NODES) ? deg[i] : 0;
    __syncthreads();
    for (int d = 128; d > 0; d >>= 1) {
        if (tid < d) s[tid] += s[tid + d];
        __syncthreads();
    }
    if (tid == 0) bsum[blockIdx.x] = s[0];
}

__global__ __launch_bounds__(256) void scan2(const int* __restrict__ bsum, int* __restrict__ boff) {
    __shared__ int s[256];
    int tid = threadIdx.x;
    int v = (tid < SCAN_NBLK) ? bsum[tid] : 0;
    s[tid] = v;
    __syncthreads();
    for (int d = 1; d < 256; d <<= 1) {
        int t = (tid >= d) ? s[tid - d] : 0;
        __syncthreads();
        s[tid] += t;
        __syncthreads();
    }
    boff[tid] = s[tid] - v;  // exclusive
}

__global__ __launch_bounds__(256) void scan3(const int* __restrict__ deg, const int* __restrict__ boff,
                                             int* __restrict__ row_ptr, int* __restrict__ nxt) {
    __shared__ int s[256];
    int tid = threadIdx.x;
    int i = blockIdx.x * 256 + tid;
    int v = (i < N_NODES) ? deg[i] : 0;
    s[tid] = v;
    __syncthreads();
    for (int d = 1; d < 256; d <<= 1) {
        int t = (tid >= d) ? s[tid - d] : 0;
        __syncthreads();
        s[tid] += t;
        __syncthreads();
    }
    int excl = s[tid] - v + boff[blockIdx.x];
    if (i < N_NODES) { row_ptr[i] = excl; nxt[i] = excl; }
    if (i == 0) row_ptr[N_NODES] = N_EDGES;
}

// scatter src index AND edge_attr row into CSR order in one pass
__global__ void scatter_edges(const int* __restrict__ ei, int* __restrict__ next_ptr,
                              const float* __restrict__ edge_attr,
                              int* __restrict__ src_s, float* __restrict__ ea_s) {
    int e = blockIdx.x * blockDim.x + threadIdx.x;
    if (e < N_EDGES) {
        int d = ei[N_EDGES + e];
        int p = atomicAdd(&next_ptr[d], 1);
        src_s[p] = ei[e];
        const float4* src = (const float4*)(edge_attr + (size_t)e * EDIM);
        float4 a0 = src[0], a1 = src[1], a2 = src[2], a3 = src[3];
        float4* dst = (float4*)(ea_s + (size_t)p * EDIM);
        dst[0] = a0; dst[1] = a1; dst[2] = a2; dst[3] = a3;
    }
}

// ---------- fused Q/K/V/Skip GEMM (LDS-staged x rows) ----------
__global__ __launch_bounds__(256) void qkvs_kernel(
    const float* __restrict__ x,
    const float* __restrict__ Wq, const float* __restrict__ bq,
    const float* __restrict__ Wk, const float* __restrict__ bk,
    const float* __restrict__ Wv, const float* __restrict__ bv,
    const float* __restrict__ Ws, const float* __restrict__ bs,
    float* __restrict__ Qo, float* __restrict__ KVo, float* __restrict__ So) {
    __shared__ float xs[QKVS_NODES][HC];
    int tid = threadIdx.x;
    int n0 = blockIdx.x * QKVS_NODES;
    for (int c = tid; c < QKVS_NODES * HC / 4; c += 256) {
        int row = c >> 4, col4 = c & 15;
        int n = n0 + row;
        float4 v = (n < N_NODES) ? ((const float4*)(x + (size_t)n * HC))[col4]
                                 : make_float4(0.f, 0.f, 0.f, 0.f);
        ((float4*)&xs[row][0])[col4] = v;
    }
    __syncthreads();
    int sel = tid >> 6;
    int j = tid & 63;
    const float* W; const float* B; float* Out; int stride; int off;
    if (sel == 0)      { W = Wq; B = bq; Out = Qo;  stride = HC;     off = 0;  }
    else if (sel == 1) { W = Wk; B = bk; Out = KVo; stride = 2 * HC; off = 0;  }
    else if (sel == 2) { W = Wv; B = bv; Out = KVo; stride = 2 * HC; off = HC; }
    else               { W = Ws; B = bs; Out = So;  stride = HC;     off = 0;  }
    float bias = B[j];
    float acc[QKVS_NODES];
#pragma unroll
    for (int n = 0; n < QKVS_NODES; n++) acc[n] = bias;
    for (int i4 = 0; i4 < HC / 4; i4++) {
        float w0 = W[(i4 * 4 + 0) * HC + j];
        float w1 = W[(i4 * 4 + 1) * HC + j];
        float w2 = W[(i4 * 4 + 2) * HC + j];
        float w3 = W[(i4 * 4 + 3) * HC + j];
#pragma unroll
        for (int n = 0; n < QKVS_NODES; n++) {
            float4 xv = ((const float4*)&xs[n][0])[i4];  // LDS broadcast
            acc[n] = fmaf(xv.x, w0, acc[n]);
            acc[n] = fmaf(xv.y, w1, acc[n]);
            acc[n] = fmaf(xv.z, w2, acc[n]);
            acc[n] = fmaf(xv.w, w3, acc[n]);
        }
    }
#pragma unroll
    for (int n = 0; n < QKVS_NODES; n++) {
        int node = n0 + n;
        if (node < N_NODES) Out[(size_t)node * stride + off + j] = acc[n];
    }
}

// ---------- attention + skip + BN + ReLU: one wave per node ----------
// inner loop batches 4 independent edge-gathers per quarter-wave round
__global__ __launch_bounds__(256) void attn_kernel(
    const float* __restrict__ Qf, const float* __restrict__ KV,
    const float* __restrict__ Sf,
    const int* __restrict__ row_ptr, const int* __restrict__ src_s,
    const float* __restrict__ ea_s, const float* __restrict__ We,
    const float* __restrict__ bng, const float* __restrict__ bnb,
    const float* __restrict__ bnm, const float* __restrict__ bnv,
    float* __restrict__ x_out) {
    __shared__ float we_s[EDIM * HC];  // 4 KB
    int tid = threadIdx.x;
    for (int c = tid; c < EDIM * HC / 4; c += 256)
        ((float4*)we_s)[c] = ((const float4*)We)[c];
    __syncthreads();

    int node = blockIdx.x * 4 + (tid >> 6);   // 12500 blocks exactly
    int lane = tid & 63;
    int quarter = lane >> 4;
    int pos = lane & 15;
    int rbeg = row_ptr[node], rend = row_ptr[node + 1];

    float4 q4 = ((const float4*)(Qf + (size_t)node * HC))[pos];
    float m = -1e30f, den = 0.f;
    float4 acc = make_float4(0.f, 0.f, 0.f, 0.f);

    int j = rbeg + quarter;
    while (j < rend) {
        float4 kb[4], vb[4], e4b[4];
        int srcs[4];
        int nb = 0;
        // how many of j, j+4, j+8, j+12 are valid, and their src indices
#pragma unroll
        for (int b = 0; b < 4; b++) {
            int jj = j + b * 4;
            if (jj < rend) { srcs[b] = src_s[jj]; nb = b + 1; }
        }
        // issue all K/V gathers (independent)
#pragma unroll
        for (int b = 0; b < 4; b++) {
            if (b < nb) {
                const float4* kv = (const float4*)(KV + (size_t)srcs[b] * 2 * HC);
                kb[b] = kv[pos];
                vb[b] = kv[16 + pos];
            }
        }
        // edge-attr loads + e_emb matvec (overlaps the K/V gathers)
#pragma unroll
        for (int b = 0; b < 4; b++) {
            if (b < nb) {
                const float4* ep = (const float4*)(ea_s + (size_t)(j + b * 4) * EDIM);
                float4 a0 = ep[0], a1 = ep[1], a2 = ep[2], a3 = ep[3];
                float eav[16] = {a0.x, a0.y, a0.z, a0.w, a1.x, a1.y, a1.z, a1.w,
                                 a2.x, a2.y, a2.z, a2.w, a3.x, a3.y, a3.z, a3.w};
                float4 e4 = make_float4(0.f, 0.f, 0.f, 0.f);
#pragma unroll
                for (int t = 0; t < EDIM; t++) {
                    float4 w4 = *((const float4*)(we_s + t * HC + pos * 4));
                    e4.x = fmaf(eav[t], w4.x, e4.x);
                    e4.y = fmaf(eav[t], w4.y, e4.y);
                    e4.z = fmaf(eav[t], w4.z, e4.z);
                    e4.w = fmaf(eav[t], w4.w, e4.w);
                }
                e4b[b] = e4;
            }
        }
        // order-preserving online-softmax chain from registers
#pragma unroll
        for (int b = 0; b < 4; b++) {
            if (b < nb) {
                float4 k4 = kb[b], v4 = vb[b], e4 = e4b[b];
                float dot = q4.x * (k4.x + e4.x) + q4.y * (k4.y + e4.y)
                          + q4.z * (k4.z + e4.z) + q4.w * (k4.w + e4.w);
                dot += __shfl_xor(dot, 1);
                dot += __shfl_xor(dot, 2);
                float logit = dot * 0.25f;
                float mn = fmaxf(m, logit);
                float corr = __expf(m - mn);
                float p = __expf(logit - mn);
                den = den * corr + p;
                acc.x = acc.x * corr + p * (v4.x + e4.x);
                acc.y = acc.y * corr + p * (v4.y + e4.y);
                acc.z = acc.z * corr + p * (v4.z + e4.z);
                acc.w = acc.w * corr + p * (v4.w + e4.w);
                m = mn;
            }
        }
        j += 16;
    }

    // merge the 4 quarter-wave softmax states
#pragma unroll
    for (int off = 16; off <= 32; off <<= 1) {
        float m2 = __shfl_xor(m, off);
        float d2 = __shfl_xor(den, off);
        float ax = __shfl_xor(acc.x, off);
        float ay = __shfl_xor(acc.y, off);
        float az = __shfl_xor(acc.z, off);
        float aw = __shfl_xor(acc.w, off);
        float mn = fmaxf(m, m2);
        float c1 = __expf(m - mn), c2 = __expf(m2 - mn);
        den = den * c1 + d2 * c2;
        acc.x = acc.x * c1 + ax * c2;
        acc.y = acc.y * c1 + ay * c2;
        acc.z = acc.z * c1 + az * c2;
        acc.w = acc.w * c1 + aw * c2;
        m = mn;
    }
    float inv = (rend > rbeg) ? 1.f / den : 0.f;
    float4 sk = ((const float4*)(Sf + (size_t)node * HC))[pos];
    float4 o = make_float4(acc.x * inv + sk.x, acc.y * inv + sk.y,
                           acc.z * inv + sk.z, acc.w * inv + sk.w);
    float4 g4 = ((const float4*)bng)[pos];
    float4 b4 = ((const float4*)bnb)[pos];
    float4 m4 = ((const float4*)bnm)[pos];
    float4 vv4 = ((const float4*)bnv)[pos];
    o.x = fmaxf((o.x - m4.x) * rsqrtf(vv4.x + BN_EPS) * g4.x + b4.x, 0.f);
    o.y = fmaxf((o.y - m4.y) * rsqrtf(vv4.y + BN_EPS) * g4.y + b4.y, 0.f);
    o.z = fmaxf((o.z - m4.z) * rsqrtf(vv4.z + BN_EPS) * g4.z + b4.z, 0.f);
    o.w = fmaxf((o.w - m4.w) * rsqrtf(vv4.w + BN_EPS) * g4.w + b4.w, 0.f);
    if (quarter == 0) ((float4*)(x_out + (size_t)node * HC))[pos] = o;
}

// ---------- graph bounds via binary search (batch is sorted) ----------
__global__ void graph_bounds(const int* __restrict__ batch, int* __restrict__ gstart) {
    int g = blockIdx.x * blockDim.x + threadIdx.x;
    if (g > NGRAPH) return;
    int lo = 0, hi = N_NODES;
    while (lo < hi) {
        int mid = (lo + hi) >> 1;
        if (batch[mid] < g) lo = mid + 1; else hi = mid;
    }
    gstart[g] = lo;
}

// ---------- fused mean-pool + MLP head: one wave per graph ----------
__global__ __launch_bounds__(256) void pool_head(
    const float* __restrict__ x, const int* __restrict__ gstart,
    const float* __restrict__ fc1_w, const float* __restrict__ fc1_b,
    const float* __restrict__ fc2_w, const float* __restrict__ fc2_b,
    float* __restrict__ out) {
    __shared__ float ps[4][HC];
    int q = threadIdx.x >> 6;
    int lane = threadIdx.x & 63;
    int g = blockIdx.x * 4 + q;           // 500 * 4 = 2000 exactly
    int beg = gstart[g], end = gstart[g + 1];
    float s = 0.f;
    for (int i = beg; i < end; i++) s += x[(size_t)i * HC + lane];  // coalesced
    float inv = (end > beg) ? 1.f / (float)(end - beg) : 1.f;
    ps[q][lane] = s * inv;
    __syncthreads();
    float o = 0.f;
    if (lane < HID) {
        float a = fc1_b[lane];
#pragma unroll
        for (int i = 0; i < HC; i++) a = fmaf(ps[q][i], fc1_w[i * HID + lane], a);
        o = fmaxf(a, 0.f) * fc2_w[lane];
    }
    o += __shfl_xor(o, 1);
    o += __shfl_xor(o, 2);
    o += __shfl_xor(o, 4);
    o += __shfl_xor(o, 8);
    if (lane == 0) out[g] = o + fc2_b[0];
}

extern "C" void kernel_launch(void* const* d_in, const int* in_sizes, int n_in,
                              void* d_out, int out_size, void* d_ws, size_t ws_size,
                              hipStream_t stream) {
    const float* x         = (const float*)d_in[0];
    const int*   ei        = (const int*)d_in[1];
    const float* edge_attr = (const float*)d_in[2];
    const int*   batch     = (const int*)d_in[3];
    const float* Wq = (const float*)d_in[4];  const float* bq = (const float*)d_in[5];
    const float* Wk = (const float*)d_in[6];  const float* bk = (const float*)d_in[7];
    const float* Wv = (const float*)d_in[8];  const float* bv = (const float*)d_in[9];
    const float* We = (const float*)d_in[10];
    const float* Ws = (const float*)d_in[11]; const float* bs = (const float*)d_in[12];
    const float* bng = (const float*)d_in[13]; const float* bnb = (const float*)d_in[14];
    const float* bnm = (const float*)d_in[15]; const float* bnv = (const float*)d_in[16];
    const float* fc1_w = (const float*)d_in[17]; const float* fc1_b = (const float*)d_in[18];
    const float* fc2_w = (const float*)d_in[19]; const float* fc2_b = (const float*)d_in[20];
    float* out = (float*)d_out;

    char* wp = (char*)d_ws;
    auto alloc = [&](size_t b) { void* p = (void*)wp; wp += (b + 255) & ~(size_t)255; return p; };
    float* xA      = (float*)alloc((size_t)N_NODES * HC * 4);
    float* xB      = (float*)alloc((size_t)N_NODES * HC * 4);
    float* Qb      = (float*)alloc((size_t)N_NODES * HC * 4);
    float* Sb      = (float*)alloc((size_t)N_NODES * HC * 4);
    float* KV      = (float*)alloc((size_t)N_NODES * 2 * HC * 4);
    int*   deg     = (int*)alloc((size_t)N_NODES * 4);
    int*   row_ptr = (int*)alloc((size_t)(N_NODES + 1) * 4);
    int*   nxt     = (int*)alloc((size_t)N_NODES * 4);
    int*   bsum    = (int*)alloc((size_t)256 * 4);
    int*   boff    = (int*)alloc((size_t)256 * 4);
    int*   src_s   = (int*)alloc((size_t)N_EDGES * 4);
    float* ea_s    = (float*)alloc((size_t)N_EDGES * EDIM * 4);
    int*   gstart  = (int*)alloc((size_t)(NGRAPH + 1) * 4);

    hipMemsetAsync(deg, 0, (size_t)N_NODES * 4, stream);

    count_deg<<<(N_EDGES + 255) / 256, 256, 0, stream>>>(ei, deg);
    scan1<<<SCAN_NBLK, 256, 0, stream>>>(deg, bsum);
    scan2<<<1, 256, 0, stream>>>(bsum, boff);
    scan3<<<SCAN_NBLK, 256, 0, stream>>>(deg, boff, row_ptr, nxt);
    scatter_edges<<<(N_EDGES + 255) / 256, 256, 0, stream>>>(ei, nxt, edge_attr, src_s, ea_s);
    graph_bounds<<<(NGRAPH + 1 + 255) / 256, 256, 0, stream>>>(batch, gstart);

    const float* xin = x;
    float* bufs[2] = {xA, xB};
    for (int l = 0; l < 3; l++) {
        float* xout = bufs[l & 1];
        qkvs_kernel<<<(N_NODES + QKVS_NODES - 1) / QKVS_NODES, 256, 0, stream>>>(
            xin, Wq + l * HC * HC, bq + l * HC, Wk + l * HC * HC, bk + l * HC,
            Wv + l * HC * HC, bv + l * HC, Ws + l * HC * HC, bs + l * HC,
            Qb, KV, Sb);
        attn_kernel<<<N_NODES / 4, 256, 0, stream>>>(
            Qb, KV, Sb, row_ptr, src_s, ea_s, We + l * EDIM * HC,
            bng + l * HC, bnb + l * HC, bnm + l * HC, bnv + l * HC, xout);
        xin = xout;
    }
    pool_head<<<NGRAPH / 4, 256, 0, stream>>>(xin, gstart, fc1_w, fc1_b, fc2_w, fc2_b, out);
}

// Round 4
// 613.528 us; speedup vs baseline: 1.5548x; 1.3583x over previous
//
#include <hip/hip_runtime.h>
#include <math.h>

#define N_NODES 50000
#define N_EDGES 800000
#define HC 64
#define HID 16
#define EDIM 16
#define NGRAPH 2000
#define BN_EPS 1e-5f
#define QKVS_NODES 32
#define SCAN_NBLK ((N_NODES + 255) / 256)   // 196

// ---------- CSR build ----------
__global__ void count_deg(const int* __restrict__ ei, int* __restrict__ deg) {
    int e = blockIdx.x * blockDim.x + threadIdx.x;
    if (e < N_EDGES) atomicAdd(&deg[ei[N_EDGES + e]], 1);
}

__global__ __launch_bounds__(256) void scan1(const int* __restrict__ deg, int* __restrict__ bsum) {
    __shared__ int s[256];
    int tid = threadIdx.x;
    int i = blockIdx.x * 256 + tid;
    s[tid] = (i < N_NODES) ? deg[i] : 0;
    __syncthreads();
    for (int d = 128; d > 0; d >>= 1) {
        if (tid < d) s[tid] += s[tid + d];
        __syncthreads();
    }
    if (tid == 0) bsum[blockIdx.x] = s[0];
}

__global__ __launch_bounds__(256) void scan2(const int* __restrict__ bsum, int* __restrict__ boff) {
    __shared__ int s[256];
    int tid = threadIdx.x;
    int v = (tid < SCAN_NBLK) ? bsum[tid] : 0;
    s[tid] = v;
    __syncthreads();
    for (int d = 1; d < 256; d <<= 1) {
        int t = (tid >= d) ? s[tid - d] : 0;
        __syncthreads();
        s[tid] += t;
        __syncthreads();
    }
    boff[tid] = s[tid] - v;  // exclusive
}

__global__ __launch_bounds__(256) void scan3(const int* __restrict__ deg, const int* __restrict__ boff,
                                             int* __restrict__ row_ptr, int* __restrict__ nxt) {
    __shared__ int s[256];
    int tid = threadIdx.x;
    int i = blockIdx.x * 256 + tid;
    int v = (i < N_NODES) ? deg[i] : 0;
    s[tid] = v;
    __syncthreads();
    for (int d = 1; d < 256; d <<= 1) {
        int t = (tid >= d) ? s[tid - d] : 0;
        __syncthreads();
        s[tid] += t;
        __syncthreads();
    }
    int excl = s[tid] - v + boff[blockIdx.x];
    if (i < N_NODES) { row_ptr[i] = excl; nxt[i] = excl; }
    if (i == 0) row_ptr[N_NODES] = N_EDGES;
}

// scatter src index AND edge_attr row into CSR order in one pass
__global__ void scatter_edges(const int* __restrict__ ei, int* __restrict__ next_ptr,
                              const float* __restrict__ edge_attr,
                              int* __restrict__ src_s, float* __restrict__ ea_s) {
    int e = blockIdx.x * blockDim.x + threadIdx.x;
    if (e < N_EDGES) {
        int d = ei[N_EDGES + e];
        int p = atomicAdd(&next_ptr[d], 1);
        src_s[p] = ei[e];
        const float4* src = (const float4*)(edge_attr + (size_t)e * EDIM);
        float4 a0 = src[0], a1 = src[1], a2 = src[2], a3 = src[3];
        float4* dst = (float4*)(ea_s + (size_t)p * EDIM);
        dst[0] = a0; dst[1] = a1; dst[2] = a2; dst[3] = a3;
    }
}

// ---------- fused Q/K/V/Skip GEMM (LDS-staged x rows) ----------
__global__ __launch_bounds__(256) void qkvs_kernel(
    const float* __restrict__ x,
    const float* __restrict__ Wq, const float* __restrict__ bq,
    const float* __restrict__ Wk, const float* __restrict__ bk,
    const float* __restrict__ Wv, const float* __restrict__ bv,
    const float* __restrict__ Ws, const float* __restrict__ bs,
    float* __restrict__ Qo, float* __restrict__ KVo, float* __restrict__ So) {
    __shared__ float xs[QKVS_NODES][HC];
    int tid = threadIdx.x;
    int n0 = blockIdx.x * QKVS_NODES;
    for (int c = tid; c < QKVS_NODES * HC / 4; c += 256) {
        int row = c >> 4, col4 = c & 15;
        int n = n0 + row;
        float4 v = (n < N_NODES) ? ((const float4*)(x + (size_t)n * HC))[col4]
                                 : make_float4(0.f, 0.f, 0.f, 0.f);
        ((float4*)&xs[row][0])[col4] = v;
    }
    __syncthreads();
    int sel = tid >> 6;
    int j = tid & 63;
    const float* W; const float* B; float* Out; int stride; int off;
    if (sel == 0)      { W = Wq; B = bq; Out = Qo;  stride = HC;     off = 0;  }
    else if (sel == 1) { W = Wk; B = bk; Out = KVo; stride = 2 * HC; off = 0;  }
    else if (sel == 2) { W = Wv; B = bv; Out = KVo; stride = 2 * HC; off = HC; }
    else               { W = Ws; B = bs; Out = So;  stride = HC;     off = 0;  }
    float bias = B[j];
    float acc[QKVS_NODES];
#pragma unroll
    for (int n = 0; n < QKVS_NODES; n++) acc[n] = bias;
    for (int i4 = 0; i4 < HC / 4; i4++) {
        float w0 = W[(i4 * 4 + 0) * HC + j];
        float w1 = W[(i4 * 4 + 1) * HC + j];
        float w2 = W[(i4 * 4 + 2) * HC + j];
        float w3 = W[(i4 * 4 + 3) * HC + j];
#pragma unroll
        for (int n = 0; n < QKVS_NODES; n++) {
            float4 xv = ((const float4*)&xs[n][0])[i4];  // LDS broadcast
            acc[n] = fmaf(xv.x, w0, acc[n]);
            acc[n] = fmaf(xv.y, w1, acc[n]);
            acc[n] = fmaf(xv.z, w2, acc[n]);
            acc[n] = fmaf(xv.w, w3, acc[n]);
        }
    }
#pragma unroll
    for (int n = 0; n < QKVS_NODES; n++) {
        int node = n0 + n;
        if (node < N_NODES) Out[(size_t)node * stride + off + j] = acc[n];
    }
}

// ---------- attention + skip + BN + ReLU: one wave per node ----------
// e_emb factored out of the edge loop:
//   logit edge term:  q.e_emb = (q@We^T).ea   -> qWe precomputed per node
//   value edge term:  sum p*e_emb = (sum p*ea)@We -> applied once in epilogue
__global__ __launch_bounds__(256) void attn_kernel(
    const float* __restrict__ Qf, const float* __restrict__ KV,
    const float* __restrict__ Sf,
    const int* __restrict__ row_ptr, const int* __restrict__ src_s,
    const float* __restrict__ ea_s, const float* __restrict__ We,
    const float* __restrict__ bng, const float* __restrict__ bnb,
    const float* __restrict__ bnm, const float* __restrict__ bnv,
    float* __restrict__ x_out) {
    __shared__ float we_s[EDIM * HC];  // 4 KB
    int tid = threadIdx.x;
    for (int c = tid; c < EDIM * HC / 4; c += 256)
        ((float4*)we_s)[c] = ((const float4*)We)[c];
    __syncthreads();

    int node = blockIdx.x * 4 + (tid >> 6);   // 12500 blocks exactly
    int lane = tid & 63;
    int quarter = lane >> 4;
    int pos = lane & 15;
    int h = pos >> 2;          // head
    int jbase = (pos & 3) * 4; // this lane's 4 edge-attr indices
    int rbeg = row_ptr[node], rend = row_ptr[node + 1];

    float4 q4 = ((const float4*)(Qf + (size_t)node * HC))[pos];

    // qWe[h][jbase+c] = sum_d q[h][d] * We[jbase+c][h*16+d]  (once per node)
    float qwe0 = 0.f, qwe1 = 0.f, qwe2 = 0.f, qwe3 = 0.f;
#pragma unroll
    for (int dd = 0; dd < 4; dd++) {
        int sl = h * 4 + dd;   // lane holding q dims h*16+dd*4 .. +3 (same in all quarters)
        float qa = __shfl(q4.x, sl), qb = __shfl(q4.y, sl);
        float qc = __shfl(q4.z, sl), qd = __shfl(q4.w, sl);
        float4 w0 = *(const float4*)(we_s + (jbase + 0) * HC + h * 16 + dd * 4);
        float4 w1 = *(const float4*)(we_s + (jbase + 1) * HC + h * 16 + dd * 4);
        float4 w2 = *(const float4*)(we_s + (jbase + 2) * HC + h * 16 + dd * 4);
        float4 w3 = *(const float4*)(we_s + (jbase + 3) * HC + h * 16 + dd * 4);
        qwe0 += qa * w0.x + qb * w0.y + qc * w0.z + qd * w0.w;
        qwe1 += qa * w1.x + qb * w1.y + qc * w1.z + qd * w1.w;
        qwe2 += qa * w2.x + qb * w2.y + qc * w2.z + qd * w2.w;
        qwe3 += qa * w3.x + qb * w3.y + qc * w3.z + qd * w3.w;
    }

    float m = -1e30f, den = 0.f;
    float4 acc = make_float4(0.f, 0.f, 0.f, 0.f);   // sum p * v
    float4 aea = make_float4(0.f, 0.f, 0.f, 0.f);   // sum p * ea (raw edge attrs)

    auto proc = [&](float4 k4, float4 ea4) -> float {
        // returns p; updates m, den
        float dot = q4.x * k4.x + q4.y * k4.y + q4.z * k4.z + q4.w * k4.w
                  + qwe0 * ea4.x + qwe1 * ea4.y + qwe2 * ea4.z + qwe3 * ea4.w;
        dot += __shfl_xor(dot, 1);
        dot += __shfl_xor(dot, 2);
        float logit = dot * 0.25f;
        float mn = fmaxf(m, logit);
        float corr = __expf(m - mn);
        float p = __expf(logit - mn);
        den = den * corr + p;
        acc.x *= corr; acc.y *= corr; acc.z *= corr; acc.w *= corr;
        aea.x *= corr; aea.y *= corr; aea.z *= corr; aea.w *= corr;
        m = mn;
        return p;
    };

    int j = rbeg + quarter;
    for (; j + 4 < rend; j += 8) {
        int s0 = src_s[j];
        int s1 = src_s[j + 4];
        const float4* kv0 = (const float4*)(KV + (size_t)s0 * 2 * HC);
        const float4* kv1 = (const float4*)(KV + (size_t)s1 * 2 * HC);
        float4 k0 = kv0[pos], v0 = kv0[16 + pos];
        float4 k1 = kv1[pos], v1 = kv1[16 + pos];
        float4 ea0 = ((const float4*)(ea_s + (size_t)j * EDIM))[pos & 3];
        float4 ea1 = ((const float4*)(ea_s + (size_t)(j + 4) * EDIM))[pos & 3];
        float p0 = proc(k0, ea0);
        acc.x = fmaf(p0, v0.x, acc.x); acc.y = fmaf(p0, v0.y, acc.y);
        acc.z = fmaf(p0, v0.z, acc.z); acc.w = fmaf(p0, v0.w, acc.w);
        aea.x = fmaf(p0, ea0.x, aea.x); aea.y = fmaf(p0, ea0.y, aea.y);
        aea.z = fmaf(p0, ea0.z, aea.z); aea.w = fmaf(p0, ea0.w, aea.w);
        float p1 = proc(k1, ea1);
        acc.x = fmaf(p1, v1.x, acc.x); acc.y = fmaf(p1, v1.y, acc.y);
        acc.z = fmaf(p1, v1.z, acc.z); acc.w = fmaf(p1, v1.w, acc.w);
        aea.x = fmaf(p1, ea1.x, aea.x); aea.y = fmaf(p1, ea1.y, aea.y);
        aea.z = fmaf(p1, ea1.z, aea.z); aea.w = fmaf(p1, ea1.w, aea.w);
    }
    if (j < rend) {
        int s0 = src_s[j];
        const float4* kv0 = (const float4*)(KV + (size_t)s0 * 2 * HC);
        float4 k0 = kv0[pos], v0 = kv0[16 + pos];
        float4 ea0 = ((const float4*)(ea_s + (size_t)j * EDIM))[pos & 3];
        float p0 = proc(k0, ea0);
        acc.x = fmaf(p0, v0.x, acc.x); acc.y = fmaf(p0, v0.y, acc.y);
        acc.z = fmaf(p0, v0.z, acc.z); acc.w = fmaf(p0, v0.w, acc.w);
        aea.x = fmaf(p0, ea0.x, aea.x); aea.y = fmaf(p0, ea0.y, aea.y);
        aea.z = fmaf(p0, ea0.z, aea.z); aea.w = fmaf(p0, ea0.w, aea.w);
    }

    // merge the 4 quarter-wave softmax states (m, den, acc, aea)
#pragma unroll
    for (int off = 16; off <= 32; off <<= 1) {
        float m2 = __shfl_xor(m, off);
        float d2 = __shfl_xor(den, off);
        float ax = __shfl_xor(acc.x, off), ay = __shfl_xor(acc.y, off);
        float az = __shfl_xor(acc.z, off), aw = __shfl_xor(acc.w, off);
        float bx = __shfl_xor(aea.x, off), by = __shfl_xor(aea.y, off);
        float bz = __shfl_xor(aea.z, off), bw = __shfl_xor(aea.w, off);
        float mn = fmaxf(m, m2);
        float c1 = __expf(m - mn), c2 = __expf(m2 - mn);
        den = den * c1 + d2 * c2;
        acc.x = acc.x * c1 + ax * c2; acc.y = acc.y * c1 + ay * c2;
        acc.z = acc.z * c1 + az * c2; acc.w = acc.w * c1 + aw * c2;
        aea.x = aea.x * c1 + bx * c2; aea.y = aea.y * c1 + by * c2;
        aea.z = aea.z * c1 + bz * c2; aea.w = aea.w * c1 + bw * c2;
        m = mn;
    }

    // epilogue: e_contrib[pos*4+c] = sum_j aggEA[h][j] * We[j][pos*4+c]
    float4 e4 = make_float4(0.f, 0.f, 0.f, 0.f);
#pragma unroll
    for (int jg = 0; jg < 4; jg++) {
        int sl = (lane & 48) | (h * 4 + jg);  // lane holding aggEA[h][jg*4 .. +3]
        float a0 = __shfl(aea.x, sl), a1 = __shfl(aea.y, sl);
        float a2 = __shfl(aea.z, sl), a3 = __shfl(aea.w, sl);
        float4 w0 = *(const float4*)(we_s + (jg * 4 + 0) * HC + pos * 4);
        float4 w1 = *(const float4*)(we_s + (jg * 4 + 1) * HC + pos * 4);
        float4 w2 = *(const float4*)(we_s + (jg * 4 + 2) * HC + pos * 4);
        float4 w3 = *(const float4*)(we_s + (jg * 4 + 3) * HC + pos * 4);
        e4.x += a0 * w0.x + a1 * w1.x + a2 * w2.x + a3 * w3.x;
        e4.y += a0 * w0.y + a1 * w1.y + a2 * w2.y + a3 * w3.y;
        e4.z += a0 * w0.z + a1 * w1.z + a2 * w2.z + a3 * w3.z;
        e4.w += a0 * w0.w + a1 * w1.w + a2 * w2.w + a3 * w3.w;
    }

    float inv = (rend > rbeg) ? 1.f / den : 0.f;
    float4 sk = ((const float4*)(Sf + (size_t)node * HC))[pos];
    float4 o = make_float4((acc.x + e4.x) * inv + sk.x, (acc.y + e4.y) * inv + sk.y,
                           (acc.z + e4.z) * inv + sk.z, (acc.w + e4.w) * inv + sk.w);
    float4 g4 = ((const float4*)bng)[pos];
    float4 b4 = ((const float4*)bnb)[pos];
    float4 m4 = ((const float4*)bnm)[pos];
    float4 vv4 = ((const float4*)bnv)[pos];
    o.x = fmaxf((o.x - m4.x) * rsqrtf(vv4.x + BN_EPS) * g4.x + b4.x, 0.f);
    o.y = fmaxf((o.y - m4.y) * rsqrtf(vv4.y + BN_EPS) * g4.y + b4.y, 0.f);
    o.z = fmaxf((o.z - m4.z) * rsqrtf(vv4.z + BN_EPS) * g4.z + b4.z, 0.f);
    o.w = fmaxf((o.w - m4.w) * rsqrtf(vv4.w + BN_EPS) * g4.w + b4.w, 0.f);
    if (quarter == 0) ((float4*)(x_out + (size_t)node * HC))[pos] = o;
}

// ---------- fused mean-pool + MLP head: one wave per graph ----------
__global__ __launch_bounds__(256) void pool_head(
    const float* __restrict__ x, const int* __restrict__ batch,
    const float* __restrict__ fc1_w, const float* __restrict__ fc1_b,
    const float* __restrict__ fc2_w, const float* __restrict__ fc2_b,
    float* __restrict__ out) {
    __shared__ float ps[4][HC];
    int q = threadIdx.x >> 6;
    int lane = threadIdx.x & 63;
    int g = blockIdx.x * 4 + q;           // 500 * 4 = 2000 exactly
    // binary-search graph bounds (batch sorted); every lane redundantly
    int lo = 0, hi = N_NODES;
    while (lo < hi) { int mid = (lo + hi) >> 1; if (batch[mid] < g) lo = mid + 1; else hi = mid; }
    int beg = lo;
    lo = 0; hi = N_NODES;
    while (lo < hi) { int mid = (lo + hi) >> 1; if (batch[mid] < g + 1) lo = mid + 1; else hi = mid; }
    int end = lo;
    float s = 0.f;
    for (int i = beg; i < end; i++) s += x[(size_t)i * HC + lane];  // coalesced
    float inv = (end > beg) ? 1.f / (float)(end - beg) : 1.f;
    ps[q][lane] = s * inv;
    __syncthreads();
    float o = 0.f;
    if (lane < HID) {
        float a = fc1_b[lane];
#pragma unroll
        for (int i = 0; i < HC; i++) a = fmaf(ps[q][i], fc1_w[i * HID + lane], a);
        o = fmaxf(a, 0.f) * fc2_w[lane];
    }
    o += __shfl_xor(o, 1);
    o += __shfl_xor(o, 2);
    o += __shfl_xor(o, 4);
    o += __shfl_xor(o, 8);
    if (lane == 0) out[g] = o + fc2_b[0];
}

extern "C" void kernel_launch(void* const* d_in, const int* in_sizes, int n_in,
                              void* d_out, int out_size, void* d_ws, size_t ws_size,
                              hipStream_t stream) {
    const float* x         = (const float*)d_in[0];
    const int*   ei        = (const int*)d_in[1];
    const float* edge_attr = (const float*)d_in[2];
    const int*   batch     = (const int*)d_in[3];
    const float* Wq = (const float*)d_in[4];  const float* bq = (const float*)d_in[5];
    const float* Wk = (const float*)d_in[6];  const float* bk = (const float*)d_in[7];
    const float* Wv = (const float*)d_in[8];  const float* bv = (const float*)d_in[9];
    const float* We = (const float*)d_in[10];
    const float* Ws = (const float*)d_in[11]; const float* bs = (const float*)d_in[12];
    const float* bng = (const float*)d_in[13]; const float* bnb = (const float*)d_in[14];
    const float* bnm = (const float*)d_in[15]; const float* bnv = (const float*)d_in[16];
    const float* fc1_w = (const float*)d_in[17]; const float* fc1_b = (const float*)d_in[18];
    const float* fc2_w = (const float*)d_in[19]; const float* fc2_b = (const float*)d_in[20];
    float* out = (float*)d_out;

    char* wp = (char*)d_ws;
    auto alloc = [&](size_t b) { void* p = (void*)wp; wp += (b + 255) & ~(size_t)255; return p; };
    float* xA      = (float*)alloc((size_t)N_NODES * HC * 4);
    float* xB      = (float*)alloc((size_t)N_NODES * HC * 4);
    float* Qb      = (float*)alloc((size_t)N_NODES * HC * 4);
    float* Sb      = (float*)alloc((size_t)N_NODES * HC * 4);
    float* KV      = (float*)alloc((size_t)N_NODES * 2 * HC * 4);
    int*   deg     = (int*)alloc((size_t)N_NODES * 4);
    int*   row_ptr = (int*)alloc((size_t)(N_NODES + 1) * 4);
    int*   nxt     = (int*)alloc((size_t)N_NODES * 4);
    int*   bsum    = (int*)alloc((size_t)256 * 4);
    int*   boff    = (int*)alloc((size_t)256 * 4);
    int*   src_s   = (int*)alloc((size_t)N_EDGES * 4);
    float* ea_s    = (float*)alloc((size_t)N_EDGES * EDIM * 4);

    hipMemsetAsync(deg, 0, (size_t)N_NODES * 4, stream);

    count_deg<<<(N_EDGES + 255) / 256, 256, 0, stream>>>(ei, deg);
    scan1<<<SCAN_NBLK, 256, 0, stream>>>(deg, bsum);
    scan2<<<1, 256, 0, stream>>>(bsum, boff);
    scan3<<<SCAN_NBLK, 256, 0, stream>>>(deg, boff, row_ptr, nxt);
    scatter_edges<<<(N_EDGES + 255) / 256, 256, 0, stream>>>(ei, nxt, edge_attr, src_s, ea_s);

    const float* xin = x;
    float* bufs[2] = {xA, xB};
    for (int l = 0; l < 3; l++) {
        float* xout = bufs[l & 1];
        qkvs_kernel<<<(N_NODES + QKVS_NODES - 1) / QKVS_NODES, 256, 0, stream>>>(
            xin, Wq + l * HC * HC, bq + l * HC, Wk + l * HC * HC, bk + l * HC,
            Wv + l * HC * HC, bv + l * HC, Ws + l * HC * HC, bs + l * HC,
            Qb, KV, Sb);
        attn_kernel<<<N_NODES / 4, 256, 0, stream>>>(
            Qb, KV, Sb, row_ptr, src_s, ea_s, We + l * EDIM * HC,
            bng + l * HC, bnb + l * HC, bnm + l * HC, bnv + l * HC, xout);
        xin = xout;
    }
    pool_head<<<NGRAPH / 4, 256, 0, stream>>>(xin, batch, fc1_w, fc1_b, fc2_w, fc2_b, out);
}